// Round 1
// baseline (397.023 us; speedup 1.0000x reference)
//
#include <hip/hip_runtime.h>

// Problem constants (fixed by setup_inputs)
#define HDIM 96
#define WDIM 96
#define HW   (HDIM * WDIM)   // 9216
#define CDIM 256
#define BDIM 32
#define RADIUS 2

// Kernel 1: one block per (b,c) row. Computes psr = (max - mean_side)/var_side.
__global__ __launch_bounds__(256) void psr_kernel(const float* __restrict__ cv,
                                                  const int* __restrict__ peaks,
                                                  float* __restrict__ psr_out) {
    const int row = blockIdx.x;                 // row in [0, B*C)
    const float4* __restrict__ p4 = (const float4*)(cv + (size_t)row * HW);

    const int py = peaks[row * 2 + 0];
    const int px = peaks[row * 2 + 1];
    // clipped 5x5 window == rectangle [y0,y1] x [x0,x1]
    const int y0 = max(0, py - RADIUS), y1 = min(HDIM - 1, py + RADIUS);
    const int x0 = max(0, px - RADIUS), x1 = min(WDIM - 1, px + RADIUS);
    const float n = (float)(HW - (y1 - y0 + 1) * (x1 - x0 + 1));

    float sum = 0.0f, sumsq = 0.0f, mx = -INFINITY;

    const int tid = threadIdx.x;
    // HW/4 = 2304 float4 per row; 256 threads -> 9 iterations, fully coalesced
    for (int i = tid; i < HW / 4; i += 256) {
        float4 v = p4[i];
        const int r  = i / (WDIM / 4);          // row index (96 % 4 == 0)
        const int c0 = (i % (WDIM / 4)) * 4;    // first col of this vec4
        const bool rin = (r >= y0) & (r <= y1);
        float vs[4] = {v.x, v.y, v.z, v.w};
#pragma unroll
        for (int k = 0; k < 4; ++k) {
            const float val = vs[k];
            mx = fmaxf(mx, val);
            const int c = c0 + k;
            const bool excl = rin & (c >= x0) & (c <= x1);
            const float m = excl ? 0.0f : val;
            sum   += m;
            sumsq += m * m;
        }
    }

    // wave-64 shuffle reduction
#pragma unroll
    for (int off = 32; off > 0; off >>= 1) {
        sum   += __shfl_down(sum, off);
        sumsq += __shfl_down(sumsq, off);
        mx     = fmaxf(mx, __shfl_down(mx, off));
    }

    __shared__ float ssum[4], ssumsq[4], smx[4];
    const int wave = tid >> 6, lane = tid & 63;
    if (lane == 0) { ssum[wave] = sum; ssumsq[wave] = sumsq; smx[wave] = mx; }
    __syncthreads();

    if (tid == 0) {
        float S = 0.0f, Q = 0.0f, M = -INFINITY;
#pragma unroll
        for (int w = 0; w < 4; ++w) {
            S += ssum[w];
            Q += ssumsq[w];
            M  = fmaxf(M, smx[w]);
        }
        const float mean = S / n;
        // sum(((x - mean)*w)^2) = Q - n*mean^2   (w in {0,1})
        const float var  = (Q - n * mean * mean) / (n - 1.0f);
        psr_out[row] = (M - mean) / var;
    }
}

// Kernel 2: one block per batch b; normalize psr by its mean over C.
__global__ __launch_bounds__(256) void saliency_kernel(const float* __restrict__ psr,
                                                       float* __restrict__ out) {
    const int b = blockIdx.x;
    const int c = threadIdx.x;                  // 256 threads == CDIM
    const float v = psr[b * CDIM + c];

    float s = v;
#pragma unroll
    for (int off = 32; off > 0; off >>= 1) s += __shfl_down(s, off);

    __shared__ float ss[4];
    if ((c & 63) == 0) ss[c >> 6] = s;
    __syncthreads();

    const float mean = (ss[0] + ss[1] + ss[2] + ss[3]) * (1.0f / CDIM);
    out[b * CDIM + c] = v / (mean + 1e-8f);
}

extern "C" void kernel_launch(void* const* d_in, const int* in_sizes, int n_in,
                              void* d_out, int out_size, void* d_ws, size_t ws_size,
                              hipStream_t stream) {
    const float* cv    = (const float*)d_in[0];   // [B, C, H, W] fp32
    const int*   peaks = (const int*)d_in[1];     // [B, C, 2] int32
    float*       out   = (float*)d_out;           // [B, C] fp32
    float*       psr   = (float*)d_ws;            // B*C floats scratch

    psr_kernel<<<BDIM * CDIM, 256, 0, stream>>>(cv, peaks, psr);
    saliency_kernel<<<BDIM, 256, 0, stream>>>(psr, out);
}

// Round 3
// 395.205 us; speedup vs baseline: 1.0046x; 1.0046x over previous
//
#include <hip/hip_runtime.h>

// Problem constants (fixed by setup_inputs)
#define HDIM 96
#define WDIM 96
#define HW   (HDIM * WDIM)   // 9216
#define CDIM 256
#define BDIM 32
#define RADIUS 2

// Kernel 1: one block per (b,c) row. Computes psr = (max - mean_side)/var_side.
// Predicated exclusion of the clipped 5x5 mainlobe window; VALU cost (~20
// ops/float4/lane ~= 100 B/cyc/CU capacity) is far below the ~10 B/cyc/CU HBM
// feed rate, so the predicate is free under the memory bound.
__global__ __launch_bounds__(256) void psr_kernel(const float* __restrict__ cv,
                                                  const int* __restrict__ peaks,
                                                  float* __restrict__ psr_out) {
    const int row = blockIdx.x;                 // row in [0, B*C)
    const float4* __restrict__ p4 = (const float4*)(cv + (size_t)row * HW);

    const int py = peaks[row * 2 + 0];
    const int px = peaks[row * 2 + 1];
    // clipped 5x5 window == rectangle [y0,y1] x [x0,x1]
    const int y0 = max(0, py - RADIUS), y1 = min(HDIM - 1, py + RADIUS);
    const int x0 = max(0, px - RADIUS), x1 = min(WDIM - 1, px + RADIUS);
    const float n = (float)(HW - (y1 - y0 + 1) * (x1 - x0 + 1));

    float sum = 0.0f, sumsq = 0.0f, mx = -INFINITY;

    const int tid = threadIdx.x;
    // HW/4 = 2304 float4 per row; 256 threads -> 9 fully-coalesced iterations
#pragma unroll
    for (int j = 0; j < 9; ++j) {
        const int i = tid + j * 256;
        float4 v = p4[i];
        const int r  = i / (WDIM / 4);          // row index (96 % 4 == 0)
        const int c0 = (i % (WDIM / 4)) * 4;    // first col of this vec4
        const bool rin = (r >= y0) & (r <= y1);
        float vs[4] = {v.x, v.y, v.z, v.w};
#pragma unroll
        for (int k = 0; k < 4; ++k) {
            const float val = vs[k];
            mx = fmaxf(mx, val);
            const int c = c0 + k;
            const bool excl = rin & (c >= x0) & (c <= x1);
            const float m = excl ? 0.0f : val;
            sum   += m;
            sumsq = fmaf(m, m, sumsq);
        }
    }

    // wave-64 shuffle reduction
#pragma unroll
    for (int off = 32; off > 0; off >>= 1) {
        sum   += __shfl_down(sum, off);
        sumsq += __shfl_down(sumsq, off);
        mx     = fmaxf(mx, __shfl_down(mx, off));
    }

    __shared__ float ssum[4], ssumsq[4], smx[4];
    const int wave = tid >> 6, lane = tid & 63;
    if (lane == 0) { ssum[wave] = sum; ssumsq[wave] = sumsq; smx[wave] = mx; }
    __syncthreads();

    if (tid == 0) {
        float S = 0.0f, Q = 0.0f, M = -INFINITY;
#pragma unroll
        for (int w = 0; w < 4; ++w) {
            S += ssum[w];
            Q += ssumsq[w];
            M  = fmaxf(M, smx[w]);
        }
        const float mean = S / n;
        // sum(((x - mean)*w)^2) = Q - n*mean^2   (w in {0,1})
        const float var  = (Q - n * mean * mean) / (n - 1.0f);
        psr_out[row] = (M - mean) / var;
    }
}

// Kernel 2: one block per batch b; normalize psr (staged in d_out) by its mean
// over C, in place. All reads of psr happen before the __syncthreads barrier;
// writes happen after — block-local, no cross-block aliasing.
__global__ __launch_bounds__(256) void saliency_kernel(float* __restrict__ psr_inout) {
    const int b = blockIdx.x;
    const int c = threadIdx.x;                  // 256 threads == CDIM
    const float v = psr_inout[b * CDIM + c];

    float s = v;
#pragma unroll
    for (int off = 32; off > 0; off >>= 1) s += __shfl_down(s, off);

    __shared__ float ss[4];
    if ((c & 63) == 0) ss[c >> 6] = s;
    __syncthreads();

    const float mean = (ss[0] + ss[1] + ss[2] + ss[3]) * (1.0f / CDIM);
    psr_inout[b * CDIM + c] = v / (mean + 1e-8f);
}

extern "C" void kernel_launch(void* const* d_in, const int* in_sizes, int n_in,
                              void* d_out, int out_size, void* d_ws, size_t ws_size,
                              hipStream_t stream) {
    const float* cv    = (const float*)d_in[0];   // [B, C, H, W] fp32
    const int*   peaks = (const int*)d_in[1];     // [B, C, 2] int32
    float*       out   = (float*)d_out;           // [B, C] fp32 — also psr staging
    (void)d_ws; (void)ws_size;

    psr_kernel<<<BDIM * CDIM, 256, 0, stream>>>(cv, peaks, out);
    saliency_kernel<<<BDIM, 256, 0, stream>>>(out);
}